// Round 15
// baseline (1335.203 us; speedup 1.0000x reference)
//
#include <hip/hip_runtime.h>
#include <hip/hip_fp16.h>

// ManualRNN: B=32, T=2048, Fin=256, H=256, O=256 (all f32 in/out)
// r15: SINGLE role-split dispatch, 576 blocks x 512 thr:
//   blocks  0-31 : scan, r10 body verbatim (799us verified) + per-chunk flags
//   blocks 32-63 : y-consumers (1/batch): y rows chunk-by-chunk behind scan
//   blocks 64-575: xh-producers: xh(f16) = x@Wxh^T+bxh, 128 rows each
// Pipeline: scan b needs xh row<=t+8 at step t (producer flags, acquire);
// y row t needs hs row t (scan chunk flags). Device-scope release/acquire
// handles XCD non-coherence (G16). Deadlock-free: waiters(64) < CUs(256),
// producers unconditional.
// xh f16 lives in y's upper half (batches 16-31 y rows); consumers c>=16
// additionally guard on xh liveness: hsflag[b0][2k'+1] set => scan b0 passed
// those xh rows => safe to overwrite with final y (transitively orders the
// producer's xh write before the consumer's y write to the same bytes).
//
// Ledger: scan step 933cy = ~620 MFMA-issue floor + ~310 serial tail (r5
// flags, r8 VALU, r9/r12 in-block fusion, r13 preread, all worse). GEMMs
// ~50us each config-invariant (r1/r10/r13/r14) -> latency-bound; overlap
// them with the scan instead of speeding them up.

typedef _Float16 f16x8 __attribute__((ext_vector_type(8)));
typedef float    f32x4 __attribute__((ext_vector_type(4)));

#define MFMA16 __builtin_amdgcn_mfma_f32_16x16x32_f16
#define AQ  __ATOMIC_ACQUIRE
#define RL  __ATOMIC_RELEASE
#define AGT __HIP_MEMORY_SCOPE_AGENT

__device__ __forceinline__ f16x8 cvt8(const float* __restrict__ p) {
    float4 u = *(const float4*)p;
    float4 v = *(const float4*)(p + 4);
    f16x8 r;
    r[0] = (_Float16)u.x; r[1] = (_Float16)u.y; r[2] = (_Float16)u.z; r[3] = (_Float16)u.w;
    r[4] = (_Float16)v.x; r[5] = (_Float16)v.y; r[6] = (_Float16)v.z; r[7] = (_Float16)v.w;
    return r;
}

// 128-row GEMM tile: C[m][n] = sum_k A[m][k]*W[n][k] + bias[n], N=K=256.
// 512 thr / 8 waves, wave owns 32 cols. A/C base pointers are block-local.
template<bool AF16, bool OF16>
__device__ __forceinline__ void gemm128(
    const void* __restrict__ Ap, const float* __restrict__ W,
    const float* __restrict__ bias, void* __restrict__ Cp, int tid) {
    const int l  = tid & 63;
    const int w  = tid >> 6;
    const int lr = l & 15;
    const int lg = l >> 4;
    const int n0 = w * 32;

    f16x8 wg[2][8];
    #pragma unroll
    for (int nt = 0; nt < 2; ++nt)
        #pragma unroll
        for (int k = 0; k < 8; ++k)
            wg[nt][k] = cvt8(W + (long)(n0 + nt * 16 + lr) * 256 + k * 32 + lg * 8);
    const float bv0 = bias[n0 + lr];
    const float bv1 = bias[n0 + 16 + lr];

    #pragma unroll 2
    for (int mt = 0; mt < 8; ++mt) {
        f32x4 ac[2] = {{0.f,0.f,0.f,0.f},{0.f,0.f,0.f,0.f}};
        #pragma unroll
        for (int k = 0; k < 8; ++k) {
            const int kc = k * 32 + lg * 8;
            f16x8 a;
            if constexpr (AF16)
                a = *(const f16x8*)((const _Float16*)Ap + (long)(mt * 16 + lr) * 256 + kc);
            else
                a = cvt8((const float*)Ap + (long)(mt * 16 + lr) * 256 + kc);
            ac[0] = MFMA16(a, wg[0][k], ac[0], 0, 0, 0);
            ac[1] = MFMA16(a, wg[1][k], ac[1], 0, 0, 0);
        }
        #pragma unroll
        for (int nt = 0; nt < 2; ++nt) {
            const int col = n0 + nt * 16 + lr;
            const float bv = nt ? bv1 : bv0;
            #pragma unroll
            for (int d = 0; d < 4; ++d) {
                const long row = mt * 16 + lg * 4 + d;
                const float v = ac[nt][d] + bv;
                if constexpr (OF16) ((_Float16*)Cp)[row * 256 + col] = (_Float16)v;
                else                ((float*)Cp)[row * 256 + col] = v;
            }
        }
    }
}

__global__ __launch_bounds__(512, 1) void rnn_all(
    const float* __restrict__ x,   const float* __restrict__ h0,
    const float* __restrict__ Wxh, const float* __restrict__ bxh,
    const float* __restrict__ Whh, const float* __restrict__ Why,
    const float* __restrict__ by,
    float* __restrict__ y,         // (65536,256) f32; upper half doubles as xh
    float* __restrict__ hfin,      // (32,256) f32
    _Float16* __restrict__ hs,     // ws: (65536,256) f16
    int* __restrict__ xhflag,      // ws+33.5MB: [16 chunks][32 batches]
    int* __restrict__ hsflag) {    // [32 batches][16 chunks]
    const int tid = threadIdx.x;
    _Float16* xhf = (_Float16*)(y + (long)32768 * 256);

    // ---------------- xh producers: blocks 64..575 ----------------
    if (blockIdx.x >= 64) {
        const int idx = blockIdx.x - 64;
        const int mc  = idx >> 5;      // row chunk 0..15
        const int b   = idx & 31;      // batch
        const long off = ((long)b * 2048 + mc * 128) * 256;
        gemm128<false, true>(x + off, Wxh, bxh, xhf + off, tid);
        __threadfence();               // per-wave: vmcnt drain + L2 writeback
        __syncthreads();               // all waves' fences done
        if (tid == 0) __hip_atomic_store(&xhflag[idx], 1, RL, AGT);
        return;
    }

    // ---------------- y consumers: blocks 32..63 ----------------
    if (blockIdx.x >= 32) {
        const int c = blockIdx.x - 32;     // batch
        for (int k = 0; k < 16; ++k) {
            // hs chunk k of batch c ready?
            while (!__hip_atomic_load(&hsflag[c * 16 + k], AQ, AGT))
                __builtin_amdgcn_s_sleep(2);
            if (c >= 16) {
                // xh-liveness: these y rows hold xh of batch b0 rows
                // [256*(k&7), +256); dead once scan b0 passed them.
                const int b0 = 2 * (c - 16) + (k >> 3);
                while (!__hip_atomic_load(&hsflag[b0 * 16 + 2 * (k & 7) + 1], AQ, AGT))
                    __builtin_amdgcn_s_sleep(2);
            }
            const long off = ((long)c * 2048 + k * 128) * 256;
            gemm128<true, false>(hs + off, Why, by, y + off, tid);
        }
        return;
    }

    // ---------------- scan: blocks 0..31 (r10 body verbatim) ----------------
    const int b   = blockIdx.x;
    const int l   = tid & 63;
    const int w   = tid >> 6;
    const int lr  = l & 15;
    const int lg  = l >> 4;
    const int n0  = w * 32;
    const int cl  = n0 + (l & 31);

    __shared__ _Float16 hbuf[2][256];

    f16x8 wb[2][8];
    #pragma unroll
    for (int nt = 0; nt < 2; ++nt)
        #pragma unroll
        for (int k = 0; k < 8; ++k)
            wb[nt][k] = cvt8(Whh + (long)(n0 + nt * 16 + lr) * 256 + k * 32 + lg * 8);

    if (tid < 256) hbuf[0][tid] = (_Float16)h0[b * 256 + tid];
    __syncthreads();

    // wait for xh chunk 0 of this batch (all lanes: per-wave acquire)
    while (!__hip_atomic_load(&xhflag[0 * 32 + b], AQ, AGT))
        __builtin_amdgcn_s_sleep(2);

    const _Float16* xp = xhf + (long)b * 2048 * 256 + cl;
    _Float16*       hp = hs  + (long)b * 2048 * 256 + cl;

    float xcur[4], xnext[4];
    #pragma unroll
    for (int j = 0; j < 4; ++j) xcur[j] = (float)xp[(long)j * 256];

    int acqd = 0;
    for (int tb = 0; tb < 2048; tb += 4) {
        // acquire next xh chunk before prefetching into it (reads tb+4..tb+7)
        const int need = (tb + 7) >> 7;
        if (need > acqd) {
            while (!__hip_atomic_load(&xhflag[need * 32 + b], AQ, AGT))
                __builtin_amdgcn_s_sleep(2);
            acqd = need;
        }

        #pragma unroll
        for (int j = 0; j < 4; ++j) {
            long tn = tb + 4 + j; if (tn > 2047) tn = 2047;
            xnext[j] = (float)xp[tn * 256];
        }

        #pragma unroll
        for (int j = 0; j < 4; ++j) {
            const f16x8* hc = (const f16x8*)hbuf[j & 1];   // t&1 == j&1
            f16x8 af[8];
            #pragma unroll
            for (int k = 0; k < 8; ++k) af[k] = hc[k * 4 + lg];

            __builtin_amdgcn_s_setprio(1);
            const f32x4 zero = {0.f, 0.f, 0.f, 0.f};
            f32x4 accA[2], accB[2];              // split chains k0-3 / k4-7
            #pragma unroll
            for (int nt = 0; nt < 2; ++nt) {
                accA[nt] = MFMA16(af[0], wb[nt][0], zero, 0, 0, 0);
                accB[nt] = MFMA16(af[4], wb[nt][4], zero, 0, 0, 0);
            }
            #pragma unroll
            for (int k = 1; k < 4; ++k)
                #pragma unroll
                for (int nt = 0; nt < 2; ++nt) {
                    accA[nt] = MFMA16(af[k],     wb[nt][k],     accA[nt], 0, 0, 0);
                    accB[nt] = MFMA16(af[k + 4], wb[nt][k + 4], accB[nt], 0, 0, 0);
                }
            __builtin_amdgcn_s_setprio(0);

            const float s0 = accA[0][0] + accB[0][0];
            const float s1 = accA[1][0] + accB[1][0];
            const float s  = ((l & 16) ? s1 : s0) + xcur[j];
            const float e  = __expf(2.0f * s);
            const float v  = 1.0f - 2.0f * __builtin_amdgcn_rcpf(e + 1.0f);
            const _Float16 hv = (_Float16)v;

            if (l < 32) {
                hbuf[(j & 1) ^ 1][cl] = hv;              // next step's h
                hp[(long)(tb + j) * 256] = hv;           // fire-and-forget
            }

            asm volatile("s_waitcnt lgkmcnt(0)" ::: "memory");
            __builtin_amdgcn_s_barrier();
            asm volatile("" ::: "memory");
        }

        // publish completed hs chunk (every 128 steps)
        if (((tb + 4) & 127) == 0) {
            __threadfence();           // each wave: drain + L2 writeback
            __syncthreads();
            if (tid == 0)
                __hip_atomic_store(&hsflag[b * 16 + ((tb + 4) >> 7) - 1], 1, RL, AGT);
        }

        #pragma unroll
        for (int j = 0; j < 4; ++j) xcur[j] = xnext[j];
    }

    // t=2047 wrote parity ((2047&1)^1)=0
    if (tid < 256) hfin[b * 256 + tid] = (float)hbuf[0][tid];
}

extern "C" void kernel_launch(void* const* d_in, const int* in_sizes, int n_in,
                              void* d_out, int out_size, void* d_ws, size_t ws_size,
                              hipStream_t stream) {
    const float* x   = (const float*)d_in[0];
    const float* h0  = (const float*)d_in[1];
    const float* Wxh = (const float*)d_in[2];
    const float* bxh = (const float*)d_in[3];
    const float* Whh = (const float*)d_in[4];
    const float* Why = (const float*)d_in[5];
    const float* by  = (const float*)d_in[6];

    float* y    = (float*)d_out;
    float* hfin = y + (long)65536 * 256;
    _Float16* hs = (_Float16*)d_ws;                       // 33.5 MB
    int* xhflag = (int*)((char*)d_ws + 33554432);         // 512 ints
    int* hsflag = xhflag + 512;                           // 512 ints

    hipMemsetAsync(xhflag, 0, 4096, stream);              // clear both flag arrays
    rnn_all<<<576, 512, 0, stream>>>(x, h0, Wxh, bxh, Whh, Why, by,
                                     y, hfin, hs, xhflag, hsflag);
}

// Round 16
// 1290.424 us; speedup vs baseline: 1.0347x; 1.0347x over previous
//
#include <hip/hip_runtime.h>
#include <hip/hip_fp16.h>

// ManualRNN: B=32, T=2048, Fin=256, H=256, O=256 (all f32 in/out)
// r16 = r15 role-split single dispatch + CU-EXCLUSIVITY via 96KiB LDS pad
// (>half of 160KiB -> 1 block/CU; scan blocks never share a CU).
//   blocks  0-31 : scan (r10 body verbatim, 799us verified) + chunk flags
//   blocks 32-63 : y-consumers (1/batch), chunk-by-chunk behind scan
//   blocks 64-575: xh-producers (128 rows each), no waits
// r15 post-mortem: VGPR=72 -> 2 blocks/CU -> GEMM blocks co-resident on scan
// CUs stole MFMA-issue/L1 slots (+500cy/step). Same mechanism explains r9/r12
// "fusion breaks scan" (same block = same CU). Fix = placement, not structure.
//
// Ledger: scan step 933cy = ~620 MFMA-issue floor + ~310 serial tail (r5
// flags, r8 VALU, r13 preread all worse). GEMMs ~50us each, config-invariant,
// latency-bound (r10/r13/r14) -> overlap on idle CUs instead of speeding up.

typedef _Float16 f16x8 __attribute__((ext_vector_type(8)));
typedef float    f32x4 __attribute__((ext_vector_type(4)));

#define MFMA16 __builtin_amdgcn_mfma_f32_16x16x32_f16
#define AQ  __ATOMIC_ACQUIRE
#define RL  __ATOMIC_RELEASE
#define AGT __HIP_MEMORY_SCOPE_AGENT

__device__ __forceinline__ f16x8 cvt8(const float* __restrict__ p) {
    float4 u = *(const float4*)p;
    float4 v = *(const float4*)(p + 4);
    f16x8 r;
    r[0] = (_Float16)u.x; r[1] = (_Float16)u.y; r[2] = (_Float16)u.z; r[3] = (_Float16)u.w;
    r[4] = (_Float16)v.x; r[5] = (_Float16)v.y; r[6] = (_Float16)v.z; r[7] = (_Float16)v.w;
    return r;
}

// 128-row GEMM tile: C[m][n] = sum_k A[m][k]*W[n][k] + bias[n], N=K=256.
template<bool AF16, bool OF16>
__device__ __forceinline__ void gemm128(
    const void* __restrict__ Ap, const float* __restrict__ W,
    const float* __restrict__ bias, void* __restrict__ Cp, int tid) {
    const int l  = tid & 63;
    const int w  = tid >> 6;
    const int lr = l & 15;
    const int lg = l >> 4;
    const int n0 = w * 32;

    f16x8 wg[2][8];
    #pragma unroll
    for (int nt = 0; nt < 2; ++nt)
        #pragma unroll
        for (int k = 0; k < 8; ++k)
            wg[nt][k] = cvt8(W + (long)(n0 + nt * 16 + lr) * 256 + k * 32 + lg * 8);
    const float bv0 = bias[n0 + lr];
    const float bv1 = bias[n0 + 16 + lr];

    #pragma unroll 2
    for (int mt = 0; mt < 8; ++mt) {
        f32x4 ac[2] = {{0.f,0.f,0.f,0.f},{0.f,0.f,0.f,0.f}};
        #pragma unroll
        for (int k = 0; k < 8; ++k) {
            const int kc = k * 32 + lg * 8;
            f16x8 a;
            if constexpr (AF16)
                a = *(const f16x8*)((const _Float16*)Ap + (long)(mt * 16 + lr) * 256 + kc);
            else
                a = cvt8((const float*)Ap + (long)(mt * 16 + lr) * 256 + kc);
            ac[0] = MFMA16(a, wg[0][k], ac[0], 0, 0, 0);
            ac[1] = MFMA16(a, wg[1][k], ac[1], 0, 0, 0);
        }
        #pragma unroll
        for (int nt = 0; nt < 2; ++nt) {
            const int col = n0 + nt * 16 + lr;
            const float bv = nt ? bv1 : bv0;
            #pragma unroll
            for (int d = 0; d < 4; ++d) {
                const long row = mt * 16 + lg * 4 + d;
                const float v = ac[nt][d] + bv;
                if constexpr (OF16) ((_Float16*)Cp)[row * 256 + col] = (_Float16)v;
                else                ((float*)Cp)[row * 256 + col] = v;
            }
        }
    }
}

__global__ __launch_bounds__(512, 1) void rnn_all(
    const float* __restrict__ x,   const float* __restrict__ h0,
    const float* __restrict__ Wxh, const float* __restrict__ bxh,
    const float* __restrict__ Whh, const float* __restrict__ Why,
    const float* __restrict__ by,
    float* __restrict__ y,         // (65536,256) f32; upper half doubles as xh
    float* __restrict__ hfin,      // (32,256) f32
    _Float16* __restrict__ hs,     // ws: (65536,256) f16
    int* __restrict__ xhflag,      // ws+33.5MB: [16 chunks][32 batches]
    int* __restrict__ hsflag) {    // [32 batches][16 chunks]
    const int tid = threadIdx.x;

    // 96 KiB LDS pad: > half of 160 KiB -> exactly 1 block/CU (exclusivity).
    // hbuf lives at the front; the rest is never touched.
    __shared__ char lds_all[98304];
    _Float16 (*hbuf)[256] = (_Float16 (*)[256])lds_all;

    _Float16* xhf = (_Float16*)(y + (long)32768 * 256);

    // ---------------- xh producers: blocks 64..575 ----------------
    if (blockIdx.x >= 64) {
        const int idx = blockIdx.x - 64;
        const int mc  = idx >> 5;      // row chunk 0..15
        const int b   = idx & 31;      // batch
        const long off = ((long)b * 2048 + mc * 128) * 256;
        gemm128<false, true>(x + off, Wxh, bxh, xhf + off, tid);
        __threadfence();               // per-wave: drain + L2 writeback
        __syncthreads();               // all waves' fences done
        if (tid == 0) __hip_atomic_store(&xhflag[idx], 1, RL, AGT);
        return;
    }

    // ---------------- y consumers: blocks 32..63 ----------------
    if (blockIdx.x >= 32) {
        const int c = blockIdx.x - 32;     // batch
        for (int k = 0; k < 16; ++k) {
            while (!__hip_atomic_load(&hsflag[c * 16 + k], AQ, AGT))
                __builtin_amdgcn_s_sleep(2);
            if (c >= 16) {
                // xh-liveness: these y rows hold xh of batch b0; dead once
                // scan b0 passed them (hsflag[b0][2(k&7)+1] released).
                const int b0 = 2 * (c - 16) + (k >> 3);
                while (!__hip_atomic_load(&hsflag[b0 * 16 + 2 * (k & 7) + 1], AQ, AGT))
                    __builtin_amdgcn_s_sleep(2);
            }
            const long off = ((long)c * 2048 + k * 128) * 256;
            gemm128<true, false>(hs + off, Why, by, y + off, tid);
        }
        return;
    }

    // ---------------- scan: blocks 0..31 (r10 body verbatim) ----------------
    const int b   = blockIdx.x;
    const int l   = tid & 63;
    const int w   = tid >> 6;
    const int lr  = l & 15;
    const int lg  = l >> 4;
    const int n0  = w * 32;
    const int cl  = n0 + (l & 31);

    f16x8 wb[2][8];
    #pragma unroll
    for (int nt = 0; nt < 2; ++nt)
        #pragma unroll
        for (int k = 0; k < 8; ++k)
            wb[nt][k] = cvt8(Whh + (long)(n0 + nt * 16 + lr) * 256 + k * 32 + lg * 8);

    if (tid < 256) hbuf[0][tid] = (_Float16)h0[b * 256 + tid];
    __syncthreads();

    while (!__hip_atomic_load(&xhflag[0 * 32 + b], AQ, AGT))
        __builtin_amdgcn_s_sleep(2);

    const _Float16* xp = xhf + (long)b * 2048 * 256 + cl;
    _Float16*       hp = hs  + (long)b * 2048 * 256 + cl;

    float xcur[4], xnext[4];
    #pragma unroll
    for (int j = 0; j < 4; ++j) xcur[j] = (float)xp[(long)j * 256];

    int acqd = 0;
    for (int tb = 0; tb < 2048; tb += 4) {
        // acquire next xh chunk before prefetching into it (reads tb+4..tb+7)
        const int need = (tb + 7) >> 7;
        if (need > acqd) {
            while (!__hip_atomic_load(&xhflag[need * 32 + b], AQ, AGT))
                __builtin_amdgcn_s_sleep(2);
            acqd = need;
        }

        #pragma unroll
        for (int j = 0; j < 4; ++j) {
            long tn = tb + 4 + j; if (tn > 2047) tn = 2047;
            xnext[j] = (float)xp[tn * 256];
        }

        #pragma unroll
        for (int j = 0; j < 4; ++j) {
            const f16x8* hc = (const f16x8*)hbuf[j & 1];   // t&1 == j&1
            f16x8 af[8];
            #pragma unroll
            for (int k = 0; k < 8; ++k) af[k] = hc[k * 4 + lg];

            __builtin_amdgcn_s_setprio(1);
            const f32x4 zero = {0.f, 0.f, 0.f, 0.f};
            f32x4 accA[2], accB[2];              // split chains k0-3 / k4-7
            #pragma unroll
            for (int nt = 0; nt < 2; ++nt) {
                accA[nt] = MFMA16(af[0], wb[nt][0], zero, 0, 0, 0);
                accB[nt] = MFMA16(af[4], wb[nt][4], zero, 0, 0, 0);
            }
            #pragma unroll
            for (int k = 1; k < 4; ++k)
                #pragma unroll
                for (int nt = 0; nt < 2; ++nt) {
                    accA[nt] = MFMA16(af[k],     wb[nt][k],     accA[nt], 0, 0, 0);
                    accB[nt] = MFMA16(af[k + 4], wb[nt][k + 4], accB[nt], 0, 0, 0);
                }
            __builtin_amdgcn_s_setprio(0);

            const float s0 = accA[0][0] + accB[0][0];
            const float s1 = accA[1][0] + accB[1][0];
            const float s  = ((l & 16) ? s1 : s0) + xcur[j];
            const float e  = __expf(2.0f * s);
            const float v  = 1.0f - 2.0f * __builtin_amdgcn_rcpf(e + 1.0f);
            const _Float16 hv = (_Float16)v;

            if (l < 32) {
                hbuf[(j & 1) ^ 1][cl] = hv;              // next step's h
                hp[(long)(tb + j) * 256] = hv;           // fire-and-forget
            }

            asm volatile("s_waitcnt lgkmcnt(0)" ::: "memory");
            __builtin_amdgcn_s_barrier();
            asm volatile("" ::: "memory");
        }

        // publish completed hs chunk (every 128 steps)
        if (((tb + 4) & 127) == 0) {
            __threadfence();
            __syncthreads();
            if (tid == 0)
                __hip_atomic_store(&hsflag[b * 16 + ((tb + 4) >> 7) - 1], 1, RL, AGT);
        }

        #pragma unroll
        for (int j = 0; j < 4; ++j) xcur[j] = xnext[j];
    }

    // t=2047 wrote parity ((2047&1)^1)=0
    if (tid < 256) hfin[b * 256 + tid] = (float)hbuf[0][tid];
}

extern "C" void kernel_launch(void* const* d_in, const int* in_sizes, int n_in,
                              void* d_out, int out_size, void* d_ws, size_t ws_size,
                              hipStream_t stream) {
    const float* x   = (const float*)d_in[0];
    const float* h0  = (const float*)d_in[1];
    const float* Wxh = (const float*)d_in[2];
    const float* bxh = (const float*)d_in[3];
    const float* Whh = (const float*)d_in[4];
    const float* Why = (const float*)d_in[5];
    const float* by  = (const float*)d_in[6];

    float* y    = (float*)d_out;
    float* hfin = y + (long)65536 * 256;
    _Float16* hs = (_Float16*)d_ws;                       // 33.5 MB
    int* xhflag = (int*)((char*)d_ws + 33554432);         // 512 ints
    int* hsflag = xhflag + 512;                           // 512 ints

    hipMemsetAsync(xhflag, 0, 4096, stream);              // clear both flag arrays
    rnn_all<<<576, 512, 0, stream>>>(x, h0, Wxh, bxh, Whh, Why, by,
                                     y, hfin, hs, xhflag, hsflag);
}

// Round 17
// 919.137 us; speedup vs baseline: 1.4527x; 1.4040x over previous
//
#include <hip/hip_runtime.h>
#include <hip/hip_fp16.h>

// ManualRNN: B=32, T=2048, Fin=256, H=256, O=256 (all f32 in/out)
// TERMINAL CONFIG (r11 reversion, best measured 919.6us):
//   phase1: xh(f16) = x @ Wxh^T + bxh  -> 2nd half of d_out y region (33.5MB)
//           epilogue via per-wave LDS transpose (64B-aligned f16x8 stores)
//   phase2: scan 799us verified: 32 blocks x 512thr, Whh in regs, LDS h
//           broadcast, LDS-only barrier, 4-deep xh prefetch, setprio
//   phase3: y(f32) = hs @ Why^T + by   -> d_out (rows>=32768 overwrite dead xh)
//
// FINAL LEDGER (16 rounds):
// - scan step 933cy = 620cy MFMA-issue floor (128 MFMA/block-step; invariant
//   under batch packing / A-row packing / wave count) + ~313cy serial
//   recurrence tail (cheapest sync = s_barrier w/ lgkmcnt-only drain).
// - fp8 K=128 MFMA would halve the issue floor but e4m3 precision (2^-4)
//   fails the 0.078 threshold by ~25x. f16 is the precision floor.
// - VALU matvec: 2x worse (compiler emits cvt+fma, not fma_mix) [r8].
// - per-step spin-flags: poll latency > barrier [r5]. Preread covers only
//   39/120cy [r13].
// - ANY multi-role/fused dispatch stretches the scan +50-60% regardless of
//   VGPR count or CU exclusivity [r9,r12,r15,r16] - mechanism unresolved
//   at this counter granularity; overlap closed.
// - GEMMs ~50us each vs 17us roofline, invariant across 5 configs
//   (tile shape, occupancy, epilogue) [r1,r10,r13,r14]; gaps ~7us/dispatch.

typedef _Float16 f16x8 __attribute__((ext_vector_type(8)));
typedef float    f32x4 __attribute__((ext_vector_type(4)));

#define MFMA16 __builtin_amdgcn_mfma_f32_16x16x32_f16

__device__ __forceinline__ f16x8 cvt8(const float* __restrict__ p) {
    float4 u = *(const float4*)p;
    float4 v = *(const float4*)(p + 4);
    f16x8 r;
    r[0] = (_Float16)u.x; r[1] = (_Float16)u.y; r[2] = (_Float16)u.z; r[3] = (_Float16)u.w;
    r[4] = (_Float16)v.x; r[5] = (_Float16)v.y; r[6] = (_Float16)v.z; r[7] = (_Float16)v.w;
    return r;
}

// C[m][n] = sum_k A[m][k]*W[n][k] + bias[n];  M-tile 128, N=K=256.
// 512 thr / 8 waves; wave w owns 32 cols; B-frags loaded once (64 VGPR).
template<bool AF16, bool OF16>
__global__ __launch_bounds__(512, 2) void gemm_nt_512(
    const void* __restrict__ Av, const float* __restrict__ W,
    const float* __restrict__ bias, void* __restrict__ Cv) {
    const int tid = threadIdx.x;
    const int l  = tid & 63;
    const int w  = tid >> 6;        // 0..7
    const int lr = l & 15;
    const int lg = l >> 4;
    const long m0 = (long)blockIdx.x * 128;
    const int  n0 = w * 32;

    __shared__ _Float16 st[8][16][40];   // [wave][row][32 cols + pad]

    f16x8 wg[2][8];
    #pragma unroll
    for (int nt = 0; nt < 2; ++nt)
        #pragma unroll
        for (int k = 0; k < 8; ++k)
            wg[nt][k] = cvt8(W + (long)(n0 + nt * 16 + lr) * 256 + k * 32 + lg * 8);

    const float bv0 = bias[n0 + lr];
    const float bv1 = bias[n0 + 16 + lr];

    #pragma unroll 2
    for (int mt = 0; mt < 8; ++mt) {
        const long r0 = m0 + mt * 16 + lr;
        f32x4 ac[2] = {{0.f,0.f,0.f,0.f},{0.f,0.f,0.f,0.f}};
        #pragma unroll
        for (int k = 0; k < 8; ++k) {
            const int kc = k * 32 + lg * 8;
            f16x8 a;
            if constexpr (AF16) a = *(const f16x8*)((const _Float16*)Av + r0 * 256 + kc);
            else                a = cvt8((const float*)Av + r0 * 256 + kc);
            ac[0] = MFMA16(a, wg[0][k], ac[0], 0, 0, 0);
            ac[1] = MFMA16(a, wg[1][k], ac[1], 0, 0, 0);
        }
        if constexpr (OF16) {
            // per-wave LDS transpose: scatter f16, read back row-contiguous
            #pragma unroll
            for (int nt = 0; nt < 2; ++nt) {
                const float bv = nt ? bv1 : bv0;
                #pragma unroll
                for (int d = 0; d < 4; ++d)
                    st[w][lg * 4 + d][nt * 16 + lr] = (_Float16)(ac[nt][d] + bv);
            }
            asm volatile("s_waitcnt lgkmcnt(0)" ::: "memory");
            const int row = l >> 2;
            const int q   = l & 3;
            f16x8 vv = *(const f16x8*)&st[w][row][q * 8];
            *( f16x8*)((_Float16*)Cv + (m0 + mt * 16 + row) * 256 + n0 + q * 8) = vv;
            asm volatile("s_waitcnt lgkmcnt(0)" ::: "memory");
        } else {
            #pragma unroll
            for (int nt = 0; nt < 2; ++nt) {
                const int col = n0 + nt * 16 + lr;
                const float bv = nt ? bv1 : bv0;
                #pragma unroll
                for (int d = 0; d < 4; ++d) {
                    const long row = m0 + mt * 16 + lg * 4 + d;
                    ((float*)Cv)[row * 256 + col] = ac[nt][d] + bv;
                }
            }
        }
    }
}

// Recurrence: 799us verified body. 32 blocks x 512 thr (8 waves, 2/SIMD).
__global__ __launch_bounds__(512, 1) void rnn_scan(
    const _Float16* __restrict__ xh, const float* __restrict__ h0,
    const float* __restrict__ Whh, _Float16* __restrict__ hs,
    float* __restrict__ hfin) {
    const int b   = blockIdx.x;
    const int tid = threadIdx.x;
    const int l   = tid & 63;
    const int w   = tid >> 6;   // 0..7
    const int lr  = l & 15;
    const int lg  = l >> 4;
    const int n0  = w * 32;

    __shared__ _Float16 hbuf[2][256];

    f16x8 wb[2][8];
    #pragma unroll
    for (int nt = 0; nt < 2; ++nt)
        #pragma unroll
        for (int k = 0; k < 8; ++k)
            wb[nt][k] = cvt8(Whh + (long)(n0 + nt * 16 + lr) * 256 + k * 32 + lg * 8);

    if (tid < 256) hbuf[0][tid] = (_Float16)h0[b * 256 + tid];
    __syncthreads();

    const int cl = n0 + (l & 31);
    const _Float16* xp = xh + (long)b * 2048 * 256 + cl;
    _Float16*       hp = hs + (long)b * 2048 * 256 + cl;

    float xcur[4], xnext[4];
    #pragma unroll
    for (int j = 0; j < 4; ++j) xcur[j] = (float)xp[(long)j * 256];

    for (int tb = 0; tb < 2048; tb += 4) {
        // next group's xh loads: ~2500cy cover >> 900cy HBM latency
        #pragma unroll
        for (int j = 0; j < 4; ++j) {
            long tn = tb + 4 + j; if (tn > 2047) tn = 2047;
            xnext[j] = (float)xp[tn * 256];
        }

        #pragma unroll
        for (int j = 0; j < 4; ++j) {
            const f16x8* hc = (const f16x8*)hbuf[j & 1];   // t&1 == j&1
            f16x8 af[8];
            #pragma unroll
            for (int k = 0; k < 8; ++k) af[k] = hc[k * 4 + lg];

            __builtin_amdgcn_s_setprio(1);
            const f32x4 zero = {0.f, 0.f, 0.f, 0.f};
            f32x4 accA[2], accB[2];              // split chains k0-3 / k4-7
            #pragma unroll
            for (int nt = 0; nt < 2; ++nt) {
                accA[nt] = MFMA16(af[0], wb[nt][0], zero, 0, 0, 0);
                accB[nt] = MFMA16(af[4], wb[nt][4], zero, 0, 0, 0);
            }
            #pragma unroll
            for (int k = 1; k < 4; ++k)
                #pragma unroll
                for (int nt = 0; nt < 2; ++nt) {
                    accA[nt] = MFMA16(af[k],     wb[nt][k],     accA[nt], 0, 0, 0);
                    accB[nt] = MFMA16(af[k + 4], wb[nt][k + 4], accB[nt], 0, 0, 0);
                }
            __builtin_amdgcn_s_setprio(0);

            // single tanh chain: select col's sum first
            const float s0 = accA[0][0] + accB[0][0];
            const float s1 = accA[1][0] + accB[1][0];
            const float s  = ((l & 16) ? s1 : s0) + xcur[j];
            const float e  = __expf(2.0f * s);
            const float v  = 1.0f - 2.0f * __builtin_amdgcn_rcpf(e + 1.0f);
            const _Float16 hv = (_Float16)v;

            if (l < 32) {
                hbuf[(j & 1) ^ 1][cl] = hv;              // next step's h
                hp[(long)(tb + j) * 256] = hv;           // fire-and-forget
            }

            // LDS-only barrier (no vmcnt drain)
            asm volatile("s_waitcnt lgkmcnt(0)" ::: "memory");
            __builtin_amdgcn_s_barrier();
            asm volatile("" ::: "memory");
        }

        #pragma unroll
        for (int j = 0; j < 4; ++j) xcur[j] = xnext[j];
    }

    // t=2047 wrote parity ((2047&1)^1)=0
    if (tid < 256) hfin[b * 256 + tid] = (float)hbuf[0][tid];
}

extern "C" void kernel_launch(void* const* d_in, const int* in_sizes, int n_in,
                              void* d_out, int out_size, void* d_ws, size_t ws_size,
                              hipStream_t stream) {
    const float* x   = (const float*)d_in[0];
    const float* h0  = (const float*)d_in[1];
    const float* Wxh = (const float*)d_in[2];
    const float* bxh = (const float*)d_in[3];
    const float* Whh = (const float*)d_in[4];
    const float* Why = (const float*)d_in[5];
    const float* by  = (const float*)d_in[6];

    float* y    = (float*)d_out;                   // (65536,256) f32
    float* hfin = y + (long)65536 * 256;           // (32,256) f32
    // xh f16 (33.5MB) in the SECOND HALF of the y region: dead before phase3
    // writes rows >= 32768 there.
    _Float16* xhf = (_Float16*)(y + (long)32768 * 256);
    _Float16* hs  = (_Float16*)d_ws;               // (65536,256) f16

    // phase1: xh(f16) = x @ Wxh^T + bxh   (LDS-transposed 64B-line stores)
    gemm_nt_512<false, true ><<<512, 512, 0, stream>>>(x, Wxh, bxh, xhf);
    // phase2: scan
    rnn_scan<<<32, 512, 0, stream>>>(xhf, h0, Whh, hs, hfin);
    // phase3: y(f32) = hs @ Why^T + by
    gemm_nt_512<true,  false><<<512, 512, 0, stream>>>(hs, Why, by, y);
}